// Round 7
// baseline (10632.365 us; speedup 1.0000x reference)
//
#include <hip/hip_runtime.h>
#include <hip/hip_fp16.h>

typedef _Float16 f16;
typedef _Float16 f16x2 __attribute__((ext_vector_type(2)));
typedef _Float16 f16x4 __attribute__((ext_vector_type(4)));
typedef _Float16 f16x8 __attribute__((ext_vector_type(8)));
typedef float    f32x4 __attribute__((ext_vector_type(4)));

#define DEVI __device__ __forceinline__

DEVI float fdot2v(f16x2 a, f16x2 b, float c){
#if __has_builtin(__builtin_amdgcn_fdot2)
  return __builtin_amdgcn_fdot2(a, b, c, false);
#else
  return c + (float)a.x * (float)b.x + (float)a.y * (float)b.y;
#endif
}
DEVI f32x4 MM(f16x8 a, f16x8 b, f32x4 c){
  return __builtin_amdgcn_mfma_f32_16x16x32_f16(a, b, c, 0, 0, 0);
}
DEVI float tanh_f(float x){ return 1.f - 2.f / (__expf(2.f * x) + 1.f); }
DEVI float sigm_f(float x){ return 1.f / (1.f + __expf(-x)); }
DEVI float leaky_f(float x){ return x >= 0.f ? x : x * (1.0f / 5.5f); }

DEVI f16x8 ld8(const f16* p){ return *(const f16x8*)p; }

DEVI float dot8(f16x8 a, f16x8 b, float acc){
  union { f16x8 v; f16x2 h[4]; } ua, ub; ua.v = a; ub.v = b;
  acc = fdot2v(ua.h[0], ub.h[0], acc);
  acc = fdot2v(ua.h[1], ub.h[1], acc);
  acc = fdot2v(ua.h[2], ub.h[2], acc);
  acc = fdot2v(ua.h[3], ub.h[3], acc);
  return acc;
}

// A-fragment loader for mfma_f32_16x16x32_f16 (verified R6).
// lane holds A[m = MT + (lane&15)][k = ks*32 + (lane>>4)*8 + j], j=0..7.
// col map: c<Kreal -> W[m*stride + c + coff]; c==tc0||tc1 -> W[m*stride];
// c==bc -> bias[m]; else 0. m >= rows -> 0.
DEVI f16x8 afrag(const float* W, const float* bias, int rows, int stride,
                 int Kreal, int coff, int tc0, int tc1, int bc,
                 int MT, int ks, int lane){
  int m  = MT + (lane & 15);
  int k0 = ks * 32 + ((lane >> 4) << 3);
  f16x8 v;
#pragma unroll
  for (int j = 0; j < 8; j++){
    int c = k0 + j; float x = 0.f;
    if (m < rows){
      if (c < Kreal)                 x = W[m * stride + c + coff];
      else if (c == tc0 || c == tc1) x = W[m * stride];
      else if (c == bc)              x = bias[m];
    }
    v[j] = (f16)x;
  }
  return v;
}

// tanh epilogue; store only lanes n16<2 (real batch cols), rows m0..m0+3 < limit
DEVI void store_tanh(f16* arr, int stride, f32x4 d, int m0, int limit, int n16){
  float v0 = tanh_f(d[0]), v1 = tanh_f(d[1]), v2 = tanh_f(d[2]), v3 = tanh_f(d[3]);
  if (n16 < 2){
    f16* dst = arr + n16 * stride + m0;
    if (m0 + 4 <= limit){
      f16x4 s; s[0]=(f16)v0; s[1]=(f16)v1; s[2]=(f16)v2; s[3]=(f16)v3;
      *(f16x4*)dst = s;
    } else {
      if (m0     < limit) dst[0] = (f16)v0;
      if (m0 + 1 < limit) dst[1] = (f16)v1;
      if (m0 + 2 < limit) dst[2] = (f16)v2;
      if (m0 + 3 < limit) dst[3] = (f16)v3;
    }
  }
}

// strides chosen so row-stride in dwords == 16 (mod 32): 2-row b128 loads are
// bank-conflict-free (8 disjoint 4-dword blocks, 8-lane broadcasts).
#define XIN_S 160   // f16: 0..99=y, 100=t_hi, 101=t_lo, 102=1.0, pad 0
#define X12_S 288   // f16: 0..274=act, 275=1.0(bias), pad 0
#define YF_S  112   // f32
#define O_S   80    // f16 decoder acts: 0..74, pad 0
#define GH_S  304   // f16
#define PA_S  64    // f32
#define OW1_S 104   // f16, 100 cols + pad 0
#define OW2_S 80    // f16, 75 cols + pad 0

// ===================== Kernel 1: encoder + latent MLP =====================
__global__ __launch_bounds__(256) void k_encode(
    const float* __restrict__ past, const float* __restrict__ h0,
    const float* __restrict__ fW1, const float* __restrict__ fb1,
    const float* __restrict__ fW2, const float* __restrict__ fb2,
    const float* __restrict__ fW3, const float* __restrict__ fb3,
    const float* __restrict__ Wih, const float* __restrict__ Whh,
    const float* __restrict__ bih, const float* __restrict__ bhh,
    const float* __restrict__ gW1, const float* __restrict__ gb1,
    const float* __restrict__ gW2, const float* __restrict__ gb2,
    const float* __restrict__ gW3, const float* __restrict__ gb3,
    float* __restrict__ gxws)
{
  __shared__ alignas(16) f16   xin[2 * XIN_S];
  __shared__ alignas(16) f16   x1s[2 * X12_S];
  __shared__ alignas(16) f16   x2s[2 * X12_S];
  __shared__ alignas(16) float yfs[2 * YF_S];
  __shared__ alignas(16) float kas[2 * YF_S];
  __shared__ alignas(16) f16   ghs[2 * GH_S];
  __shared__ alignas(16) float pas[2 * PA_S];
  __shared__ alignas(16) float wihL[300];
  __shared__ alignas(16) float bihL[300];

  const int tid = threadIdx.x, blk = blockIdx.x;
  const int lane = tid & 63, w = tid >> 6;
  const int q = lane >> 4, n16 = lane & 15;
  const int bq = q * 8;
  const int rb = n16 & 1;

  // tiles: P1/P2 18 tiles: {w,4+w,8+w,12+w} + {16+w : w<2}; P3 7: {w} + {4+w : w<3}
  const bool v5 = (w < 2);
  const bool v3b = (w < 3);
  const int t5 = 16 + w;

  f16x8 w1f[5][4], w2f[5][9], w3f[2][9];
#pragma unroll
  for (int ks = 0; ks < 4; ks++){
#pragma unroll
    for (int i = 0; i < 4; i++)
      w1f[i][ks] = afrag(fW1, fb1, 275, 101, 100, 1, 100, 101, 102, (4*i + w)*16, ks, lane);
    w1f[4][ks] = v5 ? afrag(fW1, fb1, 275, 101, 100, 1, 100, 101, 102, t5*16, ks, lane) : (f16x8)(f16)0.f;
  }
#pragma unroll
  for (int ks = 0; ks < 9; ks++){
#pragma unroll
    for (int i = 0; i < 4; i++)
      w2f[i][ks] = afrag(fW2, fb2, 275, 275, 275, 0, -1, -1, 275, (4*i + w)*16, ks, lane);
    w2f[4][ks] = v5 ? afrag(fW2, fb2, 275, 275, 275, 0, -1, -1, 275, t5*16, ks, lane) : (f16x8)(f16)0.f;
    w3f[0][ks] = afrag(fW3, fb3, 100, 275, 275, 0, -1, -1, 275, w*16, ks, lane);
    w3f[1][ks] = v3b ? afrag(fW3, fb3, 100, 275, 275, 0, -1, -1, 275, (4+w)*16, ks, lane) : (f16x8)(f16)0.f;
  }

  // zero MFMA-read LDS, stage tables
  for (int i = tid; i < 2 * XIN_S; i += 256) xin[i] = (f16)0.f;
  for (int i = tid; i < 2 * X12_S; i += 256){ x1s[i] = (f16)0.f; x2s[i] = (f16)0.f; }
  for (int i = tid; i < 128; i += 256) pas[i] = past[blk * 128 + i];
  for (int i = tid; i < 300; i += 256){ wihL[i] = Wih[i]; bihL[i] = bih[i]; }
  __syncthreads();
  if (tid < 200){
    int n = tid & 1, m = tid >> 1;
    float v = h0[(blk * 2 + n) * 100 + m];
    yfs[n * YF_S + m] = v; xin[n * XIN_S + m] = (f16)v;
  }
  if (tid < 2){
    xin[tid * XIN_S + 102] = (f16)1.f;
    x1s[tid * X12_S + 275] = (f16)1.f;
    x2s[tid * X12_S + 275] = (f16)1.f;
    float t0 = pas[tid * PA_S] - 1.f;
    f16 th = (f16)t0;
    xin[tid * XIN_S + 100] = th;
    xin[tid * XIN_S + 101] = (f16)(t0 - (float)th);
  }
  __syncthreads();

  const f16* xinB = xin + rb * XIN_S;
  const f16* x1B  = x1s + rb * X12_S;
  const f16* x2B  = x2s + rb * X12_S;

#pragma unroll 1
  for (int st = 0; st < 32; st++){
#pragma unroll 1
    for (int g = 0; g < 8; g++){
      // ---- P1: stage 1 ----
      {
        f32x4 a0={0,0,0,0}, a1=a0, a2=a0, a3=a0, a4=a0;
#pragma unroll
        for (int ks = 0; ks < 4; ks++){
          f16x8 b = ld8(xinB + ks * 32 + bq);
          a0 = MM(w1f[0][ks], b, a0); a1 = MM(w1f[1][ks], b, a1);
          a2 = MM(w1f[2][ks], b, a2); a3 = MM(w1f[3][ks], b, a3);
          if (v5) a4 = MM(w1f[4][ks], b, a4);
        }
        store_tanh(x1s, X12_S, a0, (w     )*16 + q*4, 275, n16);
        store_tanh(x1s, X12_S, a1, (4 + w )*16 + q*4, 275, n16);
        store_tanh(x1s, X12_S, a2, (8 + w )*16 + q*4, 275, n16);
        store_tanh(x1s, X12_S, a3, (12 + w)*16 + q*4, 275, n16);
        if (v5) store_tanh(x1s, X12_S, a4, t5*16 + q*4, 275, n16);
      }
      __syncthreads();
      // ---- P2: stage 2 ----
      {
        f32x4 a0={0,0,0,0}, a1=a0, a2=a0, a3=a0, a4=a0;
#pragma unroll
        for (int ks = 0; ks < 9; ks++){
          f16x8 b = ld8(x1B + ks * 32 + bq);
          a0 = MM(w2f[0][ks], b, a0); a1 = MM(w2f[1][ks], b, a1);
          a2 = MM(w2f[2][ks], b, a2); a3 = MM(w2f[3][ks], b, a3);
          if (v5) a4 = MM(w2f[4][ks], b, a4);
        }
        store_tanh(x2s, X12_S, a0, (w     )*16 + q*4, 275, n16);
        store_tanh(x2s, X12_S, a1, (4 + w )*16 + q*4, 275, n16);
        store_tanh(x2s, X12_S, a2, (8 + w )*16 + q*4, 275, n16);
        store_tanh(x2s, X12_S, a3, (12 + w)*16 + q*4, 275, n16);
        if (v5) store_tanh(x2s, X12_S, a4, t5*16 + q*4, 275, n16);
      }
      __syncthreads();
      // ---- P3: stage 3 + RK glue ----
      {
        f32x4 d0={0,0,0,0}, d1=d0;
#pragma unroll
        for (int ks = 0; ks < 9; ks++){
          f16x8 b = ld8(x2B + ks * 32 + bq);
          d0 = MM(w3f[0][ks], b, d0);
          if (v3b) d1 = MM(w3f[1][ks], b, d1);
        }
        float tc = pas[rb * PA_S + 2 * st];
        float tp = (st == 0) ? tc - 1.f : pas[rb * PA_S + 2 * st - 2];
        float dt = (tc - tp) * 0.5f;
#pragma unroll
        for (int jt = 0; jt < 2; jt++){
          if (jt == 1 && !v3b) break;
          int m0 = (jt == 0 ? w : 4 + w) * 16 + q * 4;
          if (n16 < 2 && m0 + 3 < 100){
            f32x4 d = (jt == 0) ? d0 : d1;
            f32x4 kv;
            kv[0]=tanh_f(d[0]); kv[1]=tanh_f(d[1]); kv[2]=tanh_f(d[2]); kv[3]=tanh_f(d[3]);
            float* yp = yfs + n16 * YF_S + m0;
            float* kp = kas + n16 * YF_S + m0;
            f16*   xp = xin + n16 * XIN_S + m0;
            f32x4 yv = *(f32x4*)yp, yst;
            int e = g & 3;
            if (e == 0){ *(f32x4*)kp = kv;                        yst = yv + 0.5f*dt*kv; }
            else if (e == 1){ *(f32x4*)kp = *(f32x4*)kp + 2.f*kv; yst = yv + 0.5f*dt*kv; }
            else if (e == 2){ *(f32x4*)kp = *(f32x4*)kp + 2.f*kv; yst = yv + dt*kv; }
            else { f32x4 yn = yv + dt*(*(f32x4*)kp + kv)*(1.f/6.f); *(f32x4*)yp = yn; yst = yn; }
            f16x4 xs; xs[0]=(f16)yst[0]; xs[1]=(f16)yst[1]; xs[2]=(f16)yst[2]; xs[3]=(f16)yst[3];
            *(f16x4*)xp = xs;
          }
        }
        if (tid < 2 && g < 7){
          int gn = g + 1;
          float tcc = pas[tid * PA_S + 2 * st];
          float tpp = (st == 0) ? tcc - 1.f : pas[tid * PA_S + 2 * st - 2];
          float dt2 = (tcc - tpp) * 0.5f;
          float ce = (gn & 3) == 0 ? 0.f : ((gn & 3) == 3 ? 1.f : 0.5f);
          float t = tpp + (float)(gn >> 2) * dt2 + ce * dt2;
          f16 th = (f16)t;
          xin[tid * XIN_S + 100] = th;
          xin[tid * XIN_S + 101] = (f16)(t - (float)th);
        }
      }
      __syncthreads();
    }
    // ---- P4: gh = Whh @ h + bhh (on-the-fly A-frags; 19 tiles) ----
    {
      f16x8 b0 = ld8(xinB + 0 + bq),  b1 = ld8(xinB + 32 + bq),
            b2 = ld8(xinB + 64 + bq), b3 = ld8(xinB + 96 + bq);
#pragma unroll
      for (int i = 0; i < 5; i++){
        int tg = 4 * i + w;
        if (i == 4 && w >= 3) break;
        int MT = tg * 16;
        f32x4 d = {0,0,0,0};
        d = MM(afrag(Whh, bhh, 300, 100, 100, 0, -1, -1, 102, MT, 0, lane), b0, d);
        d = MM(afrag(Whh, bhh, 300, 100, 100, 0, -1, -1, 102, MT, 1, lane), b1, d);
        d = MM(afrag(Whh, bhh, 300, 100, 100, 0, -1, -1, 102, MT, 2, lane), b2, d);
        d = MM(afrag(Whh, bhh, 300, 100, 100, 0, -1, -1, 102, MT, 3, lane), b3, d);
        int m0 = MT + q * 4;
        if (n16 < 2 && m0 + 4 <= 300){
          f16x4 s; s[0]=(f16)d[0]; s[1]=(f16)d[1]; s[2]=(f16)d[2]; s[3]=(f16)d[3];
          *(f16x4*)(ghs + n16 * GH_S + m0) = s;
        }
      }
    }
    __syncthreads();
    // ---- P5: GRU gates ----
    if (tid < 200){
      int n = tid & 1, j = tid >> 1;
      float x = pas[n * PA_S + 2 * st + 1];
      float r  = sigm_f(x * wihL[j]       + bihL[j]       + (float)ghs[n * GH_S + j]);
      float z  = sigm_f(x * wihL[100 + j] + bihL[100 + j] + (float)ghs[n * GH_S + 100 + j]);
      float nn = tanh_f(x * wihL[200 + j] + bihL[200 + j] + r * (float)ghs[n * GH_S + 200 + j]);
      float h = yfs[n * YF_S + j];
      float hn = (1.f - z) * nn + z * h;
      yfs[n * YF_S + j] = hn;
      xin[n * XIN_S + j] = (f16)hn;
    }
    if (tid < 2 && st < 31){
      float t = pas[tid * PA_S + 2 * st];   // next interval starts at times[st]
      f16 th = (f16)t;
      xin[tid * XIN_S + 100] = th;
      xin[tid * XIN_S + 101] = (f16)(t - (float)th);
    }
    __syncthreads();
  }

  // ---- latent MLP (f32, once) ----
  float* o1f = (float*)x1s;   // [2][76]
  float* o2f = (float*)x2s;
  if (tid < 150){
    int n = tid & 1, j = tid >> 1;
    float a = gb1[j];
    for (int k = 0; k < 100; k++) a += gW1[j * 100 + k] * yfs[n * YF_S + k];
    o1f[n * 76 + j] = leaky_f(a);
  }
  __syncthreads();
  if (tid < 150){
    int n = tid & 1, j = tid >> 1;
    float a = gb2[j];
    for (int k = 0; k < 75; k++) a += gW2[j * 75 + k] * o1f[n * 76 + k];
    o2f[n * 76 + j] = leaky_f(a);
  }
  __syncthreads();
  if (tid < 4){
    int n = tid & 1, j = tid >> 1;
    float a = gb3[j];
    for (int k = 0; k < 75; k++) a += gW3[j * 75 + k] * o2f[n * 76 + k];
    gxws[(blk * 2 + n) * 2 + j] = a;
  }
}

// ===================== Kernel 2: z0 + forecast ODE + decoder =====================
__global__ __launch_bounds__(256) void k_forecast(
    const float* __restrict__ t_future, const float* __restrict__ eps,
    const float* __restrict__ fW1, const float* __restrict__ fb1,
    const float* __restrict__ fW2, const float* __restrict__ fb2,
    const float* __restrict__ fW3, const float* __restrict__ fb3,
    const float* __restrict__ oW1, const float* __restrict__ ob1,
    const float* __restrict__ oW2, const float* __restrict__ ob2,
    const float* __restrict__ oW3, const float* __restrict__ ob3,
    const float* __restrict__ gxws, float* __restrict__ out)
{
  __shared__ alignas(16) f16   xin[2 * XIN_S];
  __shared__ alignas(16) f16   x1s[2 * X12_S];
  __shared__ alignas(16) f16   x2s[2 * X12_S];
  __shared__ alignas(16) float yfs[2 * YF_S];
  __shared__ alignas(16) float kas[2 * YF_S];
  __shared__ alignas(16) f16   o1s[2 * O_S];
  __shared__ alignas(16) f16   o2s[2 * O_S];
  __shared__ alignas(16) float tfs[2 * 256];
  __shared__ alignas(16) f16   oW1L[75 * OW1_S];
  __shared__ alignas(16) f16   oW2L[75 * OW2_S];
  __shared__ alignas(16) f16   ow3L[80];
  __shared__ alignas(16) float ob1L[75];
  __shared__ alignas(16) float ob2L[75];

  const int tid = threadIdx.x, blk = blockIdx.x;
  const int lane = tid & 63, w = tid >> 6;
  const int q = lane >> 4, n16 = lane & 15;
  const int bq = q * 8;
  const int rb = n16 & 1;

  const bool v5 = (w < 2);
  const bool v3b = (w < 3);
  const int t5 = 16 + w;

  f16x8 w1f[5][4], w2f[5][9], w3f[2][9];
#pragma unroll
  for (int ks = 0; ks < 4; ks++){
#pragma unroll
    for (int i = 0; i < 4; i++)
      w1f[i][ks] = afrag(fW1, fb1, 275, 101, 100, 1, 100, 101, 102, (4*i + w)*16, ks, lane);
    w1f[4][ks] = v5 ? afrag(fW1, fb1, 275, 101, 100, 1, 100, 101, 102, t5*16, ks, lane) : (f16x8)(f16)0.f;
  }
#pragma unroll
  for (int ks = 0; ks < 9; ks++){
#pragma unroll
    for (int i = 0; i < 4; i++)
      w2f[i][ks] = afrag(fW2, fb2, 275, 275, 275, 0, -1, -1, 275, (4*i + w)*16, ks, lane);
    w2f[4][ks] = v5 ? afrag(fW2, fb2, 275, 275, 275, 0, -1, -1, 275, t5*16, ks, lane) : (f16x8)(f16)0.f;
    w3f[0][ks] = afrag(fW3, fb3, 100, 275, 275, 0, -1, -1, 275, w*16, ks, lane);
    w3f[1][ks] = v3b ? afrag(fW3, fb3, 100, 275, 275, 0, -1, -1, 275, (4+w)*16, ks, lane) : (f16x8)(f16)0.f;
  }
  const float ob3v = ob3[0];

  // zero + stage
  for (int i = tid; i < 2 * XIN_S; i += 256) xin[i] = (f16)0.f;
  for (int i = tid; i < 2 * X12_S; i += 256){ x1s[i] = (f16)0.f; x2s[i] = (f16)0.f; }
  for (int i = tid; i < 2 * O_S; i += 256){ o1s[i] = (f16)0.f; o2s[i] = (f16)0.f; }
  for (int i = tid; i < 512; i += 256) tfs[i] = t_future[blk * 512 + i];
  for (int i = tid; i < 75 * OW1_S; i += 256){
    int r = i / OW1_S, c = i - r * OW1_S;
    oW1L[i] = (c < 100) ? (f16)oW1[r * 100 + c] : (f16)0.f;
  }
  for (int i = tid; i < 75 * OW2_S; i += 256){
    int r = i / OW2_S, c = i - r * OW2_S;
    oW2L[i] = (c < 75) ? (f16)oW2[r * 75 + c] : (f16)0.f;
  }
  if (tid < 80) ow3L[tid] = (tid < 75) ? (f16)oW3[tid] : (f16)0.f;
  if (tid < 75){ ob1L[tid] = ob1[tid]; ob2L[tid] = ob2[tid]; }
  __syncthreads();
  if (tid < 200){
    int n = tid & 1, m = tid >> 1;
    int r = blk * 2 + n;
    float loc, scl;
    if (r < 128){ loc = gxws[4 * r];              scl = gxws[4 * r + 2]; }
    else        { loc = fabsf(gxws[4 * r - 511]); scl = fabsf(gxws[4 * r - 509]); }
    float v = loc + scl * eps[m * 256 + r];
    yfs[n * YF_S + m] = v; xin[n * XIN_S + m] = (f16)v;
  }
  if (tid < 2){
    xin[tid * XIN_S + 102] = (f16)1.f;
    x1s[tid * X12_S + 275] = (f16)1.f;
    x2s[tid * X12_S + 275] = (f16)1.f;
    float t0 = tfs[tid * 256];
    f16 th = (f16)t0;
    xin[tid * XIN_S + 100] = th;
    xin[tid * XIN_S + 101] = (f16)(t0 - (float)th);
  }
  __syncthreads();

  const f16* xinB = xin + rb * XIN_S;
  const f16* x1B  = x1s + rb * X12_S;
  const f16* x2B  = x2s + rb * X12_S;

#pragma unroll 1
  for (int iv = 0; iv < 255; iv++){
#pragma unroll 1
    for (int g = 0; g < 8; g++){
      const bool dec = (g == 0);
      // ---- P1: S1 MFMA (+ decoder L1 on start-of-interval state) ----
      {
        f32x4 a0={0,0,0,0}, a1=a0, a2=a0, a3=a0, a4=a0;
#pragma unroll
        for (int ks = 0; ks < 4; ks++){
          f16x8 b = ld8(xinB + ks * 32 + bq);
          a0 = MM(w1f[0][ks], b, a0); a1 = MM(w1f[1][ks], b, a1);
          a2 = MM(w1f[2][ks], b, a2); a3 = MM(w1f[3][ks], b, a3);
          if (v5) a4 = MM(w1f[4][ks], b, a4);
        }
        if (dec && tid < 150){
          int n = tid & 1, j = tid >> 1;
          float a = ob1L[j];
          const f16x8* wr = (const f16x8*)(oW1L + j * OW1_S);
          const f16x8* xr = (const f16x8*)(xin + n * XIN_S);
#pragma unroll
          for (int c = 0; c < 13; c++) a = dot8(wr[c], xr[c], a);  // w pads 0 kill t cols
          o1s[n * O_S + j] = (f16)leaky_f(a);
        }
        store_tanh(x1s, X12_S, a0, (w     )*16 + q*4, 275, n16);
        store_tanh(x1s, X12_S, a1, (4 + w )*16 + q*4, 275, n16);
        store_tanh(x1s, X12_S, a2, (8 + w )*16 + q*4, 275, n16);
        store_tanh(x1s, X12_S, a3, (12 + w)*16 + q*4, 275, n16);
        if (v5) store_tanh(x1s, X12_S, a4, t5*16 + q*4, 275, n16);
      }
      __syncthreads();
      // ---- P2: S2 MFMA (+ decoder L2) ----
      {
        f32x4 a0={0,0,0,0}, a1=a0, a2=a0, a3=a0, a4=a0;
#pragma unroll
        for (int ks = 0; ks < 9; ks++){
          f16x8 b = ld8(x1B + ks * 32 + bq);
          a0 = MM(w2f[0][ks], b, a0); a1 = MM(w2f[1][ks], b, a1);
          a2 = MM(w2f[2][ks], b, a2); a3 = MM(w2f[3][ks], b, a3);
          if (v5) a4 = MM(w2f[4][ks], b, a4);
        }
        if (dec && tid < 150){
          int n = tid & 1, j = tid >> 1;
          float a = ob2L[j];
          const f16x8* wr = (const f16x8*)(oW2L + j * OW2_S);
          const f16x8* xr = (const f16x8*)(o1s + n * O_S);
#pragma unroll
          for (int c = 0; c < 10; c++) a = dot8(wr[c], xr[c], a);  // pads 0 both sides
          o2s[n * O_S + j] = (f16)leaky_f(a);
        }
        store_tanh(x2s, X12_S, a0, (w     )*16 + q*4, 275, n16);
        store_tanh(x2s, X12_S, a1, (4 + w )*16 + q*4, 275, n16);
        store_tanh(x2s, X12_S, a2, (8 + w )*16 + q*4, 275, n16);
        store_tanh(x2s, X12_S, a3, (12 + w)*16 + q*4, 275, n16);
        if (v5) store_tanh(x2s, X12_S, a4, t5*16 + q*4, 275, n16);
      }
      __syncthreads();
      // ---- P3: S3 MFMA + RK glue + t-next (+ decoder L3) ----
      {
        f32x4 d0={0,0,0,0}, d1=d0;
#pragma unroll
        for (int ks = 0; ks < 9; ks++){
          f16x8 b = ld8(x2B + ks * 32 + bq);
          d0 = MM(w3f[0][ks], b, d0);
          if (v3b) d1 = MM(w3f[1][ks], b, d1);
        }
        float tp = tfs[rb * 256 + iv], tc = tfs[rb * 256 + iv + 1];
        float dt = (tc - tp) * 0.5f;
#pragma unroll
        for (int jt = 0; jt < 2; jt++){
          if (jt == 1 && !v3b) break;
          int m0 = (jt == 0 ? w : 4 + w) * 16 + q * 4;
          if (n16 < 2 && m0 + 3 < 100){
            f32x4 d = (jt == 0) ? d0 : d1;
            f32x4 kv;
            kv[0]=tanh_f(d[0]); kv[1]=tanh_f(d[1]); kv[2]=tanh_f(d[2]); kv[3]=tanh_f(d[3]);
            float* yp = yfs + n16 * YF_S + m0;
            float* kp = kas + n16 * YF_S + m0;
            f16*   xp = xin + n16 * XIN_S + m0;
            f32x4 yv = *(f32x4*)yp, yst;
            int e = g & 3;
            if (e == 0){ *(f32x4*)kp = kv;                        yst = yv + 0.5f*dt*kv; }
            else if (e == 1){ *(f32x4*)kp = *(f32x4*)kp + 2.f*kv; yst = yv + 0.5f*dt*kv; }
            else if (e == 2){ *(f32x4*)kp = *(f32x4*)kp + 2.f*kv; yst = yv + dt*kv; }
            else { f32x4 yn = yv + dt*(*(f32x4*)kp + kv)*(1.f/6.f); *(f32x4*)yp = yn; yst = yn; }
            f16x4 xs; xs[0]=(f16)yst[0]; xs[1]=(f16)yst[1]; xs[2]=(f16)yst[2]; xs[3]=(f16)yst[3];
            *(f16x4*)xp = xs;
          }
        }
        if (tid < 2){
          int gn = g + 1, ivn = iv;
          if (gn == 8){ gn = 0; ivn = iv + 1; }
          if (ivn < 255){
            float tpp = tfs[tid * 256 + ivn], tcc = tfs[tid * 256 + ivn + 1];
            float dt2 = (tcc - tpp) * 0.5f;
            float ce = (gn & 3) == 0 ? 0.f : ((gn & 3) == 3 ? 1.f : 0.5f);
            float t = tpp + (float)(gn >> 2) * dt2 + ce * dt2;
            f16 th = (f16)t;
            xin[tid * XIN_S + 100] = th;
            xin[tid * XIN_S + 101] = (f16)(t - (float)th);
          }
        }
        if (dec && tid < 2){
          float a = 0.f;
          const f16x2* wv = (const f16x2*)ow3L;
          const f16x2* xv = (const f16x2*)(o2s + tid * O_S);
#pragma unroll
          for (int j = 0; j < 38; j++) a = fdot2v(wv[j], xv[j], a);  // pads 0
          out[(blk * 2 + tid) * 256 + iv] = a + ob3v;
        }
      }
      __syncthreads();
    }
  }
  // ---- final decode (tf = 255) on post-loop state ----
  if (tid < 150){
    int n = tid & 1, j = tid >> 1;
    float a = ob1L[j];
    const f16x8* wr = (const f16x8*)(oW1L + j * OW1_S);
    const f16x8* xr = (const f16x8*)(xin + n * XIN_S);
#pragma unroll
    for (int c = 0; c < 13; c++) a = dot8(wr[c], xr[c], a);
    o1s[n * O_S + j] = (f16)leaky_f(a);
  }
  __syncthreads();
  if (tid < 150){
    int n = tid & 1, j = tid >> 1;
    float a = ob2L[j];
    const f16x8* wr = (const f16x8*)(oW2L + j * OW2_S);
    const f16x8* xr = (const f16x8*)(o1s + n * O_S);
#pragma unroll
    for (int c = 0; c < 10; c++) a = dot8(wr[c], xr[c], a);
    o2s[n * O_S + j] = (f16)leaky_f(a);
  }
  __syncthreads();
  if (tid < 2){
    float a = 0.f;
    const f16x2* wv = (const f16x2*)ow3L;
    const f16x2* xv = (const f16x2*)(o2s + tid * O_S);
#pragma unroll
    for (int j = 0; j < 38; j++) a = fdot2v(wv[j], xv[j], a);
    out[(blk * 2 + tid) * 256 + 255] = a + ob3v;
  }
}

extern "C" void kernel_launch(void* const* d_in, const int* in_sizes, int n_in,
                              void* d_out, int out_size, void* d_ws, size_t ws_size,
                              hipStream_t stream) {
  (void)in_sizes; (void)n_in; (void)out_size; (void)ws_size;
  const float* past     = (const float*)d_in[0];
  const float* h0       = (const float*)d_in[1];
  const float* t_future = (const float*)d_in[2];
  const float* eps      = (const float*)d_in[3];
  const float* fW1 = (const float*)d_in[4];  const float* fb1 = (const float*)d_in[5];
  const float* fW2 = (const float*)d_in[6];  const float* fb2 = (const float*)d_in[7];
  const float* fW3 = (const float*)d_in[8];  const float* fb3 = (const float*)d_in[9];
  const float* Wih = (const float*)d_in[10]; const float* Whh = (const float*)d_in[11];
  const float* bih = (const float*)d_in[12]; const float* bhh = (const float*)d_in[13];
  const float* gW1 = (const float*)d_in[14]; const float* gb1 = (const float*)d_in[15];
  const float* gW2 = (const float*)d_in[16]; const float* gb2 = (const float*)d_in[17];
  const float* gW3 = (const float*)d_in[18]; const float* gb3 = (const float*)d_in[19];
  const float* oW1 = (const float*)d_in[20]; const float* ob1 = (const float*)d_in[21];
  const float* oW2 = (const float*)d_in[22]; const float* ob2 = (const float*)d_in[23];
  const float* oW3 = (const float*)d_in[24]; const float* ob3 = (const float*)d_in[25];
  float* gxws = (float*)d_ws;
  float* out = (float*)d_out;

  hipLaunchKernelGGL(k_encode, dim3(128), dim3(256), 0, stream,
      past, h0, fW1, fb1, fW2, fb2, fW3, fb3,
      Wih, Whh, bih, bhh, gW1, gb1, gW2, gb2, gW3, gb3, gxws);
  hipLaunchKernelGGL(k_forecast, dim3(128), dim3(256), 0, stream,
      t_future, eps, fW1, fb1, fW2, fb2, fW3, fb3,
      oW1, ob1, oW2, ob2, oW3, ob3, gxws, out);
}

// Round 8
// 6661.412 us; speedup vs baseline: 1.5961x; 1.5961x over previous
//
#include <hip/hip_runtime.h>
#include <hip/hip_fp16.h>

typedef _Float16 f16;
typedef _Float16 f16x2 __attribute__((ext_vector_type(2)));
typedef _Float16 f16x4 __attribute__((ext_vector_type(4)));
typedef _Float16 f16x8 __attribute__((ext_vector_type(8)));
typedef float    f32x4 __attribute__((ext_vector_type(4)));

#define DEVI __device__ __forceinline__

DEVI float fdot2v(f16x2 a, f16x2 b, float c){
#if __has_builtin(__builtin_amdgcn_fdot2)
  return __builtin_amdgcn_fdot2(a, b, c, false);
#else
  return c + (float)a.x * (float)b.x + (float)a.y * (float)b.y;
#endif
}
DEVI f32x4 MM(f16x8 a, f16x8 b, f32x4 c){
  return __builtin_amdgcn_mfma_f32_16x16x32_f16(a, b, c, 0, 0, 0);
}
DEVI float tanh_f(float x){ return 1.f - 2.f / (__expf(2.f * x) + 1.f); }
DEVI float sigm_f(float x){ return 1.f / (1.f + __expf(-x)); }
DEVI float leaky_f(float x){ return x >= 0.f ? x : x * (1.0f / 5.5f); }

DEVI f16x8 ld8(const f16* p){ return *(const f16x8*)p; }

DEVI float dot8(f16x8 a, f16x8 b, float acc){
  union { f16x8 v; f16x2 h[4]; } ua, ub; ua.v = a; ub.v = b;
  acc = fdot2v(ua.h[0], ub.h[0], acc);
  acc = fdot2v(ua.h[1], ub.h[1], acc);
  acc = fdot2v(ua.h[2], ub.h[2], acc);
  acc = fdot2v(ua.h[3], ub.h[3], acc);
  return acc;
}

// A-fragment loader for mfma_f32_16x16x32_f16 (layout verified R6/R7).
// lane holds A[m = MT + (lane&15)][k = ks*32 + (lane>>4)*8 + j], j=0..7.
// col map: c<Kreal -> W[m*stride + c + coff]; c==tc0||tc1 -> W[m*stride];
// c==bc -> bias[m]; else 0. m >= rows -> 0.
DEVI f16x8 afrag(const float* W, const float* bias, int rows, int stride,
                 int Kreal, int coff, int tc0, int tc1, int bc,
                 int MT, int ks, int lane){
  int m  = MT + (lane & 15);
  int k0 = ks * 32 + ((lane >> 4) << 3);
  f16x8 v;
#pragma unroll
  for (int j = 0; j < 8; j++){
    int c = k0 + j; float x = 0.f;
    if (m < rows){
      if (c < Kreal)                 x = W[m * stride + c + coff];
      else if (c == tc0 || c == tc1) x = W[m * stride];
      else if (c == bc)              x = bias[m];
    }
    v[j] = (f16)x;
  }
  return v;
}

// strides: act rows ≡ 16 dwords (mod 32) -> 2-row B-frag b128 reads conflict-free
#define XIN_S 160   // f16: 0..99=y, 100=t_hi, 101=t_lo, 102=1.0, pad 0
#define X12_S 288   // f16: 0..274=act, 275=1.0(bias), pad 0
#define R1_S  304   // f32 raw stage1/2 pre-activations
#define R3_S  112   // f32 raw stage3
#define YF_S  112   // f32
#define GH_S  304   // f16
#define PA_S  64    // f32
#define O_S   80    // f16 decoder acts, pad 0
#define OW1_S 104   // f16 weights row, pad 0
#define OW2_S 80

// ===================== Kernel 1: encoder + latent MLP =====================
__global__ __launch_bounds__(512, 2) void k_encode(
    const float* __restrict__ past, const float* __restrict__ h0,
    const float* __restrict__ fW1, const float* __restrict__ fb1,
    const float* __restrict__ fW2, const float* __restrict__ fb2,
    const float* __restrict__ fW3, const float* __restrict__ fb3,
    const float* __restrict__ Wih, const float* __restrict__ Whh,
    const float* __restrict__ bih, const float* __restrict__ bhh,
    const float* __restrict__ gW1, const float* __restrict__ gb1,
    const float* __restrict__ gW2, const float* __restrict__ gb2,
    const float* __restrict__ gW3, const float* __restrict__ gb3,
    float* __restrict__ gxws)
{
  __shared__ alignas(16) f16   xin[2 * XIN_S];
  __shared__ alignas(16) f16   x1s[2 * X12_S];
  __shared__ alignas(16) f16   x2s[2 * X12_S];
  __shared__ alignas(16) float r1 [2 * R1_S];
  __shared__ alignas(16) float r3 [2 * R3_S];
  __shared__ alignas(16) float yfs[2 * YF_S];
  __shared__ alignas(16) float kas[2 * YF_S];
  __shared__ alignas(16) f16   ghs[2 * GH_S];
  __shared__ alignas(16) float pas[2 * PA_S];
  __shared__ alignas(16) float wihL[300];
  __shared__ alignas(16) float bihL[300];

  const int tid = threadIdx.x, blk = blockIdx.x;
  const int lane = tid & 63, w = tid >> 6;
  const int q = lane >> 4, n16 = lane & 15;
  const int bq = q * 8;
  const int rb = n16 & 1;

  const bool is2 = (w < 4);
  const bool is1 = (w == 4 || w == 5);

  // weight fragments: union array, role-dependent contents
  f16x8 wf[45];
  if (is2){
#pragma unroll
    for (int i = 0; i < 4; i++)
#pragma unroll
      for (int ks = 0; ks < 9; ks++)
        wf[i * 9 + ks] = afrag(fW2, fb2, 275, 275, 275, 0, -1, -1, 275, (4*i + w)*16, ks, lane);
#pragma unroll
    for (int ks = 0; ks < 9; ks++)
      wf[36 + ks] = (w < 2) ? afrag(fW2, fb2, 275, 275, 275, 0, -1, -1, 275, (16+w)*16, ks, lane)
                            : (f16x8)(f16)0.f;
  } else if (is1){
#pragma unroll
    for (int i = 0; i < 9; i++)
#pragma unroll
      for (int ks = 0; ks < 4; ks++)
        wf[i * 4 + ks] = afrag(fW1, fb1, 275, 101, 100, 1, 100, 101, 102, (2*i + (w&1))*16, ks, lane);
#pragma unroll
    for (int i = 36; i < 45; i++) wf[i] = (f16x8)(f16)0.f;
  } else {
    const int nt = (w == 6) ? 4 : 3;
#pragma unroll
    for (int i = 0; i < 4; i++)
#pragma unroll
      for (int ks = 0; ks < 9; ks++)
        wf[i * 9 + ks] = (i < nt) ? afrag(fW3, fb3, 100, 275, 275, 0, -1, -1, 275, (2*i + (w&1))*16, ks, lane)
                                  : (f16x8)(f16)0.f;
#pragma unroll
    for (int i = 36; i < 45; i++) wf[i] = (f16x8)(f16)0.f;
  }

  // init
  for (int i = tid; i < 2 * XIN_S; i += 512) xin[i] = (f16)0.f;
  for (int i = tid; i < 2 * X12_S; i += 512){ x1s[i] = (f16)0.f; x2s[i] = (f16)0.f; }
  for (int i = tid; i < 128; i += 512) pas[i] = past[blk * 128 + i];
  for (int i = tid; i < 300; i += 512){ wihL[i] = Wih[i]; bihL[i] = bih[i]; }
  __syncthreads();
  if (tid < 200){
    int n = tid & 1, m = tid >> 1;
    float v = h0[(blk * 2 + n) * 100 + m];
    yfs[n * YF_S + m] = v; xin[n * XIN_S + m] = (f16)v;
  }
  if (tid < 2){
    xin[tid * XIN_S + 102] = (f16)1.f;
    x1s[tid * X12_S + 275] = (f16)1.f;
    x2s[tid * X12_S + 275] = (f16)1.f;
    float t0 = pas[tid * PA_S] - 1.f;
    f16 th = (f16)t0;
    xin[tid * XIN_S + 100] = th;
    xin[tid * XIN_S + 101] = (f16)(t0 - (float)th);
  }
  __syncthreads();

  const f16* xinB = xin + rb * XIN_S;
  const f16* x1B  = x1s + rb * X12_S;
  const f16* x2B  = x2s + rb * X12_S;

#pragma unroll 1
  for (int st = 0; st < 32; st++){
#pragma unroll 1
    for (int g = 0; g < 8; g++){
      // ---- P1: stage 1 (waves 4-5), two 5/4-tile rounds ----
      if (is1){
#pragma unroll
        for (int half = 0; half < 2; half++){
          const int ntt = half ? 4 : 5;
          f32x4 acc[5];
#pragma unroll
          for (int i = 0; i < 5; i++) acc[i] = (f32x4){0.f,0.f,0.f,0.f};
#pragma unroll
          for (int ks = 0; ks < 4; ks++){
            f16x8 b = ld8(xinB + ks * 32 + bq);
#pragma unroll
            for (int i = 0; i < 5; i++)
              if (i < ntt) acc[i] = MM(wf[(half * 5 + i) * 4 + ks], b, acc[i]);
          }
          if (n16 < 2){
#pragma unroll
            for (int i = 0; i < 5; i++)
              if (i < ntt){
                int tile = 2 * (half * 5 + i) + (w & 1);
                *(f32x4*)(r1 + n16 * R1_S + tile * 16 + q * 4) = acc[i];
              }
          }
        }
      }
      __syncthreads();
      // ---- P1b: tanh(r1) -> x1s (550 values over 512 threads) ----
      {
        int j = tid >> 1, n = tid & 1;
        x1s[n * X12_S + j] = (f16)tanh_f(r1[n * R1_S + j]);
        int v = tid + 512;
        if (v < 550){
          int j2 = v >> 1, n2 = v & 1;
          x1s[n2 * X12_S + j2] = (f16)tanh_f(r1[n2 * R1_S + j2]);
        }
      }
      __syncthreads();
      // ---- P2: stage 2 (waves 0-3) ----
      if (is2){
        f32x4 acc[5];
#pragma unroll
        for (int i = 0; i < 5; i++) acc[i] = (f32x4){0.f,0.f,0.f,0.f};
#pragma unroll
        for (int ks = 0; ks < 9; ks++){
          f16x8 b = ld8(x1B + ks * 32 + bq);
          acc[0] = MM(wf[ks],      b, acc[0]);
          acc[1] = MM(wf[9 + ks],  b, acc[1]);
          acc[2] = MM(wf[18 + ks], b, acc[2]);
          acc[3] = MM(wf[27 + ks], b, acc[3]);
          if (w < 2) acc[4] = MM(wf[36 + ks], b, acc[4]);
        }
        if (n16 < 2){
#pragma unroll
          for (int i = 0; i < 4; i++)
            *(f32x4*)(r1 + n16 * R1_S + (4*i + w) * 16 + q * 4) = acc[i];
          if (w < 2)
            *(f32x4*)(r1 + n16 * R1_S + (16 + w) * 16 + q * 4) = acc[4];
        }
      }
      __syncthreads();
      // ---- P2b: tanh(r1) -> x2s ----
      {
        int j = tid >> 1, n = tid & 1;
        x2s[n * X12_S + j] = (f16)tanh_f(r1[n * R1_S + j]);
        int v = tid + 512;
        if (v < 550){
          int j2 = v >> 1, n2 = v & 1;
          x2s[n2 * X12_S + j2] = (f16)tanh_f(r1[n2 * R1_S + j2]);
        }
      }
      __syncthreads();
      // ---- P3: stage 3 (waves 6-7) ----
      if (!is2 && !is1){
        const int nt = (w == 6) ? 4 : 3;
        f32x4 acc[4];
#pragma unroll
        for (int i = 0; i < 4; i++) acc[i] = (f32x4){0.f,0.f,0.f,0.f};
#pragma unroll
        for (int ks = 0; ks < 9; ks++){
          f16x8 b = ld8(x2B + ks * 32 + bq);
#pragma unroll
          for (int i = 0; i < 4; i++)
            if (i < nt) acc[i] = MM(wf[i * 9 + ks], b, acc[i]);
        }
        if (n16 < 2){
#pragma unroll
          for (int i = 0; i < 4; i++)
            if (i < nt)
              *(f32x4*)(r3 + n16 * R3_S + (2*i + (w&1)) * 16 + q * 4) = acc[i];
        }
      }
      __syncthreads();
      // ---- P3b: RK glue (200 thr) + t-update ----
      if (tid < 200){
        int m = tid >> 1, n = tid & 1;
        float tc = pas[n * PA_S + 2 * st];
        float tp = (st == 0) ? tc - 1.f : pas[n * PA_S + 2 * st - 2];
        float dt = (tc - tp) * 0.5f;
        float kv = tanh_f(r3[n * R3_S + m]);
        float y  = yfs[n * YF_S + m];
        float ka = kas[n * YF_S + m];
        float yst;
        int e = g & 3;
        if (e == 0){ kas[n * YF_S + m] = kv;            yst = y + 0.5f * dt * kv; }
        else if (e == 1){ kas[n * YF_S + m] = ka + 2.f * kv; yst = y + 0.5f * dt * kv; }
        else if (e == 2){ kas[n * YF_S + m] = ka + 2.f * kv; yst = y + dt * kv; }
        else { float yn = y + dt * (ka + kv) * (1.f / 6.f); yfs[n * YF_S + m] = yn; yst = yn; }
        xin[n * XIN_S + m] = (f16)yst;
      }
      if (tid < 2 && g < 7){
        int gn = g + 1;
        float tcc = pas[tid * PA_S + 2 * st];
        float tpp = (st == 0) ? tcc - 1.f : pas[tid * PA_S + 2 * st - 2];
        float dt2 = (tcc - tpp) * 0.5f;
        float ce = (gn & 3) == 0 ? 0.f : ((gn & 3) == 3 ? 1.f : 0.5f);
        float t = tpp + (float)(gn >> 2) * dt2 + ce * dt2;
        f16 th = (f16)t;
        xin[tid * XIN_S + 100] = th;
        xin[tid * XIN_S + 101] = (f16)(t - (float)th);
      }
      __syncthreads();
    }
    // ---- P4: gh = Whh @ h + bhh (waves 0-3, on-the-fly frags) ----
    if (is2){
      f16x8 b0 = ld8(xinB + 0  + bq), b1 = ld8(xinB + 32 + bq),
            b2 = ld8(xinB + 64 + bq), b3 = ld8(xinB + 96 + bq);
#pragma unroll
      for (int i = 0; i < 5; i++){
        bool val = (i < 4) || (w < 3);
        int MT = ((i < 4) ? (4*i + w) : (16 + w)) * 16;
        f32x4 d = {0.f,0.f,0.f,0.f};
        d = MM(afrag(Whh, bhh, 300, 100, 100, 0, -1, -1, 102, MT, 0, lane), b0, d);
        d = MM(afrag(Whh, bhh, 300, 100, 100, 0, -1, -1, 102, MT, 1, lane), b1, d);
        d = MM(afrag(Whh, bhh, 300, 100, 100, 0, -1, -1, 102, MT, 2, lane), b2, d);
        d = MM(afrag(Whh, bhh, 300, 100, 100, 0, -1, -1, 102, MT, 3, lane), b3, d);
        if (val && n16 < 2){
          f16x4 s; s[0]=(f16)d[0]; s[1]=(f16)d[1]; s[2]=(f16)d[2]; s[3]=(f16)d[3];
          *(f16x4*)(ghs + n16 * GH_S + MT + q * 4) = s;
        }
      }
    }
    __syncthreads();
    // ---- P5: GRU gates ----
    if (tid < 200){
      int n = tid & 1, j = tid >> 1;
      float x = pas[n * PA_S + 2 * st + 1];
      float r  = sigm_f(x * wihL[j]       + bihL[j]       + (float)ghs[n * GH_S + j]);
      float z  = sigm_f(x * wihL[100 + j] + bihL[100 + j] + (float)ghs[n * GH_S + 100 + j]);
      float nn = tanh_f(x * wihL[200 + j] + bihL[200 + j] + r * (float)ghs[n * GH_S + 200 + j]);
      float h = yfs[n * YF_S + j];
      float hn = (1.f - z) * nn + z * h;
      yfs[n * YF_S + j] = hn;
      xin[n * XIN_S + j] = (f16)hn;
    }
    if (tid < 2 && st < 31){
      float t = pas[tid * PA_S + 2 * st];   // next interval starts at times[st]
      f16 th = (f16)t;
      xin[tid * XIN_S + 100] = th;
      xin[tid * XIN_S + 101] = (f16)(t - (float)th);
    }
    __syncthreads();
  }

  // ---- latent MLP (f32, once) ----
  float* o1f = r1;   // [n*76+j]
  float* o2f = r3;
  if (tid < 150){
    int n = tid & 1, j = tid >> 1;
    float a = gb1[j];
    for (int k = 0; k < 100; k++) a += gW1[j * 100 + k] * yfs[n * YF_S + k];
    o1f[n * 76 + j] = leaky_f(a);
  }
  __syncthreads();
  if (tid < 150){
    int n = tid & 1, j = tid >> 1;
    float a = gb2[j];
    for (int k = 0; k < 75; k++) a += gW2[j * 75 + k] * o1f[n * 76 + k];
    o2f[n * 76 + j] = leaky_f(a);
  }
  __syncthreads();
  if (tid < 4){
    int n = tid & 1, j = tid >> 1;
    float a = gb3[j];
    for (int k = 0; k < 75; k++) a += gW3[j * 75 + k] * o2f[n * 76 + k];
    gxws[(blk * 2 + n) * 2 + j] = a;
  }
}

// ===================== Kernel 2: z0 + forecast ODE + decoder =====================
__global__ __launch_bounds__(512, 2) void k_forecast(
    const float* __restrict__ t_future, const float* __restrict__ eps,
    const float* __restrict__ fW1, const float* __restrict__ fb1,
    const float* __restrict__ fW2, const float* __restrict__ fb2,
    const float* __restrict__ fW3, const float* __restrict__ fb3,
    const float* __restrict__ oW1, const float* __restrict__ ob1,
    const float* __restrict__ oW2, const float* __restrict__ ob2,
    const float* __restrict__ oW3, const float* __restrict__ ob3,
    const float* __restrict__ gxws, float* __restrict__ out)
{
  __shared__ alignas(16) f16   xin[2 * XIN_S];
  __shared__ alignas(16) f16   x1s[2 * X12_S];
  __shared__ alignas(16) f16   x2s[2 * X12_S];
  __shared__ alignas(16) float r1 [2 * R1_S];
  __shared__ alignas(16) float r3 [2 * R3_S];
  __shared__ alignas(16) float yfs[2 * YF_S];
  __shared__ alignas(16) float kas[2 * YF_S];
  __shared__ alignas(16) float tfs[2 * 256];
  __shared__ alignas(16) f16   o1s[2 * O_S];
  __shared__ alignas(16) f16   o2s[2 * O_S];
  __shared__ alignas(16) f16   oW1L[75 * OW1_S];
  __shared__ alignas(16) f16   oW2L[75 * OW2_S];
  __shared__ alignas(16) f16   ow3L[80];
  __shared__ alignas(16) float ob1L[75];
  __shared__ alignas(16) float ob2L[75];

  const int tid = threadIdx.x, blk = blockIdx.x;
  const int lane = tid & 63, w = tid >> 6;
  const int q = lane >> 4, n16 = lane & 15;
  const int bq = q * 8;
  const int rb = n16 & 1;

  const bool is2 = (w < 4);
  const bool is1 = (w == 4 || w == 5);
  const bool is3 = (w == 6 || w == 7);

  f16x8 wf[45];
  if (is2){
#pragma unroll
    for (int i = 0; i < 4; i++)
#pragma unroll
      for (int ks = 0; ks < 9; ks++)
        wf[i * 9 + ks] = afrag(fW2, fb2, 275, 275, 275, 0, -1, -1, 275, (4*i + w)*16, ks, lane);
#pragma unroll
    for (int ks = 0; ks < 9; ks++)
      wf[36 + ks] = (w < 2) ? afrag(fW2, fb2, 275, 275, 275, 0, -1, -1, 275, (16+w)*16, ks, lane)
                            : (f16x8)(f16)0.f;
  } else if (is1){
#pragma unroll
    for (int i = 0; i < 9; i++)
#pragma unroll
      for (int ks = 0; ks < 4; ks++)
        wf[i * 4 + ks] = afrag(fW1, fb1, 275, 101, 100, 1, 100, 101, 102, (2*i + (w&1))*16, ks, lane);
#pragma unroll
    for (int i = 36; i < 45; i++) wf[i] = (f16x8)(f16)0.f;
  } else {
    const int nt = (w == 6) ? 4 : 3;
#pragma unroll
    for (int i = 0; i < 4; i++)
#pragma unroll
      for (int ks = 0; ks < 9; ks++)
        wf[i * 9 + ks] = (i < nt) ? afrag(fW3, fb3, 100, 275, 275, 0, -1, -1, 275, (2*i + (w&1))*16, ks, lane)
                                  : (f16x8)(f16)0.f;
#pragma unroll
    for (int i = 36; i < 45; i++) wf[i] = (f16x8)(f16)0.f;
  }
  const float ob3v = ob3[0];

  // init
  for (int i = tid; i < 2 * XIN_S; i += 512) xin[i] = (f16)0.f;
  for (int i = tid; i < 2 * X12_S; i += 512){ x1s[i] = (f16)0.f; x2s[i] = (f16)0.f; }
  for (int i = tid; i < 2 * O_S; i += 512){ o1s[i] = (f16)0.f; o2s[i] = (f16)0.f; }
  for (int i = tid; i < 512; i += 512) tfs[i] = t_future[blk * 512 + i];
  for (int i = tid; i < 75 * OW1_S; i += 512){
    int r = i / OW1_S, c = i - r * OW1_S;
    oW1L[i] = (c < 100) ? (f16)oW1[r * 100 + c] : (f16)0.f;
  }
  for (int i = tid; i < 75 * OW2_S; i += 512){
    int r = i / OW2_S, c = i - r * OW2_S;
    oW2L[i] = (c < 75) ? (f16)oW2[r * 75 + c] : (f16)0.f;
  }
  if (tid < 80) ow3L[tid] = (tid < 75) ? (f16)oW3[tid] : (f16)0.f;
  if (tid < 75){ ob1L[tid] = ob1[tid]; ob2L[tid] = ob2[tid]; }
  __syncthreads();
  if (tid < 200){
    int n = tid & 1, m = tid >> 1;
    int r = blk * 2 + n;
    float loc, scl;
    if (r < 128){ loc = gxws[4 * r];              scl = gxws[4 * r + 2]; }
    else        { loc = fabsf(gxws[4 * r - 511]); scl = fabsf(gxws[4 * r - 509]); }
    float v = loc + scl * eps[m * 256 + r];
    yfs[n * YF_S + m] = v; xin[n * XIN_S + m] = (f16)v;
  }
  if (tid < 2){
    xin[tid * XIN_S + 102] = (f16)1.f;
    x1s[tid * X12_S + 275] = (f16)1.f;
    x2s[tid * X12_S + 275] = (f16)1.f;
    float t0 = tfs[tid * 256];
    f16 th = (f16)t0;
    xin[tid * XIN_S + 100] = th;
    xin[tid * XIN_S + 101] = (f16)(t0 - (float)th);
  }
  __syncthreads();

  const f16* xinB = xin + rb * XIN_S;
  const f16* x1B  = x1s + rb * X12_S;
  const f16* x2B  = x2s + rb * X12_S;

  auto decL1 = [&](){   // call from waves 6-7 only
    int idx = tid - 384;
    int j = idx >> 1, n = idx & 1;
    float a = ob1L[j];
    const f16x8* wr = (const f16x8*)(oW1L + j * OW1_S);
    const f16x8* xr = (const f16x8*)(xin + n * XIN_S);
#pragma unroll
    for (int c = 0; c < 13; c++) a = dot8(wr[c], xr[c], a);
    o1s[n * O_S + j] = (f16)leaky_f(a);
    if (idx < 22){
      int j2 = 64 + (idx >> 1);
      float a2 = ob1L[j2];
      const f16x8* wr2 = (const f16x8*)(oW1L + j2 * OW1_S);
#pragma unroll
      for (int c = 0; c < 13; c++) a2 = dot8(wr2[c], xr[c], a2);
      o1s[n * O_S + j2] = (f16)leaky_f(a2);
    }
  };
  auto decL2 = [&](){   // call from waves 4-5 only
    int idx = tid - 256;
    int j = idx >> 1, n = idx & 1;
    float a = ob2L[j];
    const f16x8* wr = (const f16x8*)(oW2L + j * OW2_S);
    const f16x8* xr = (const f16x8*)(o1s + n * O_S);
#pragma unroll
    for (int c = 0; c < 10; c++) a = dot8(wr[c], xr[c], a);
    o2s[n * O_S + j] = (f16)leaky_f(a);
    if (idx < 22){
      int j2 = 64 + (idx >> 1);
      float a2 = ob2L[j2];
      const f16x8* wr2 = (const f16x8*)(oW2L + j2 * OW2_S);
#pragma unroll
      for (int c = 0; c < 10; c++) a2 = dot8(wr2[c], xr[c], a2);
      o2s[n * O_S + j2] = (f16)leaky_f(a2);
    }
  };
  auto decL3 = [&](int tf){   // tid 504/505
    int n = tid - 504;
    float a = 0.f;
    const f16x2* wv = (const f16x2*)ow3L;
    const f16x2* xv = (const f16x2*)(o2s + n * O_S);
#pragma unroll
    for (int j = 0; j < 38; j++) a = fdot2v(wv[j], xv[j], a);
    out[(blk * 2 + n) * 256 + tf] = a + ob3v;
  };

#pragma unroll 1
  for (int iv = 0; iv < 255; iv++){
#pragma unroll 1
    for (int g = 0; g < 8; g++){
      const bool dec = (g == 0);
      // ---- P1: stage1 (w4-5); decoder L1 (w6-7, every 8th) ----
      if (is1){
#pragma unroll
        for (int half = 0; half < 2; half++){
          const int ntt = half ? 4 : 5;
          f32x4 acc[5];
#pragma unroll
          for (int i = 0; i < 5; i++) acc[i] = (f32x4){0.f,0.f,0.f,0.f};
#pragma unroll
          for (int ks = 0; ks < 4; ks++){
            f16x8 b = ld8(xinB + ks * 32 + bq);
#pragma unroll
            for (int i = 0; i < 5; i++)
              if (i < ntt) acc[i] = MM(wf[(half * 5 + i) * 4 + ks], b, acc[i]);
          }
          if (n16 < 2){
#pragma unroll
            for (int i = 0; i < 5; i++)
              if (i < ntt){
                int tile = 2 * (half * 5 + i) + (w & 1);
                *(f32x4*)(r1 + n16 * R1_S + tile * 16 + q * 4) = acc[i];
              }
          }
        }
      } else if (is3 && dec){
        decL1();
      }
      __syncthreads();
      // ---- P1b ----
      {
        int j = tid >> 1, n = tid & 1;
        x1s[n * X12_S + j] = (f16)tanh_f(r1[n * R1_S + j]);
        int v = tid + 512;
        if (v < 550){
          int j2 = v >> 1, n2 = v & 1;
          x1s[n2 * X12_S + j2] = (f16)tanh_f(r1[n2 * R1_S + j2]);
        }
      }
      __syncthreads();
      // ---- P2: stage2 (w0-3); decoder L2 (w4-5, every 8th) ----
      if (is2){
        f32x4 acc[5];
#pragma unroll
        for (int i = 0; i < 5; i++) acc[i] = (f32x4){0.f,0.f,0.f,0.f};
#pragma unroll
        for (int ks = 0; ks < 9; ks++){
          f16x8 b = ld8(x1B + ks * 32 + bq);
          acc[0] = MM(wf[ks],      b, acc[0]);
          acc[1] = MM(wf[9 + ks],  b, acc[1]);
          acc[2] = MM(wf[18 + ks], b, acc[2]);
          acc[3] = MM(wf[27 + ks], b, acc[3]);
          if (w < 2) acc[4] = MM(wf[36 + ks], b, acc[4]);
        }
        if (n16 < 2){
#pragma unroll
          for (int i = 0; i < 4; i++)
            *(f32x4*)(r1 + n16 * R1_S + (4*i + w) * 16 + q * 4) = acc[i];
          if (w < 2)
            *(f32x4*)(r1 + n16 * R1_S + (16 + w) * 16 + q * 4) = acc[4];
        }
      } else if (is1 && dec){
        decL2();
      }
      __syncthreads();
      // ---- P2b ----
      {
        int j = tid >> 1, n = tid & 1;
        x2s[n * X12_S + j] = (f16)tanh_f(r1[n * R1_S + j]);
        int v = tid + 512;
        if (v < 550){
          int j2 = v >> 1, n2 = v & 1;
          x2s[n2 * X12_S + j2] = (f16)tanh_f(r1[n2 * R1_S + j2]);
        }
      }
      __syncthreads();
      // ---- P3: stage3 (w6-7) ----
      if (is3){
        const int nt = (w == 6) ? 4 : 3;
        f32x4 acc[4];
#pragma unroll
        for (int i = 0; i < 4; i++) acc[i] = (f32x4){0.f,0.f,0.f,0.f};
#pragma unroll
        for (int ks = 0; ks < 9; ks++){
          f16x8 b = ld8(x2B + ks * 32 + bq);
#pragma unroll
          for (int i = 0; i < 4; i++)
            if (i < nt) acc[i] = MM(wf[i * 9 + ks], b, acc[i]);
        }
        if (n16 < 2){
#pragma unroll
          for (int i = 0; i < 4; i++)
            if (i < nt)
              *(f32x4*)(r3 + n16 * R3_S + (2*i + (w&1)) * 16 + q * 4) = acc[i];
        }
      }
      __syncthreads();
      // ---- P3b: RK glue + t-update + decoder L3 ----
      if (tid < 200){
        int m = tid >> 1, n = tid & 1;
        float tp = tfs[n * 256 + iv], tc = tfs[n * 256 + iv + 1];
        float dt = (tc - tp) * 0.5f;
        float kv = tanh_f(r3[n * R3_S + m]);
        float y  = yfs[n * YF_S + m];
        float ka = kas[n * YF_S + m];
        float yst;
        int e = g & 3;
        if (e == 0){ kas[n * YF_S + m] = kv;                 yst = y + 0.5f * dt * kv; }
        else if (e == 1){ kas[n * YF_S + m] = ka + 2.f * kv; yst = y + 0.5f * dt * kv; }
        else if (e == 2){ kas[n * YF_S + m] = ka + 2.f * kv; yst = y + dt * kv; }
        else { float yn = y + dt * (ka + kv) * (1.f / 6.f); yfs[n * YF_S + m] = yn; yst = yn; }
        xin[n * XIN_S + m] = (f16)yst;
      }
      if (tid < 2){
        int gn = g + 1, ivn = iv;
        if (gn == 8){ gn = 0; ivn = iv + 1; }
        if (ivn < 255){
          float tpp = tfs[tid * 256 + ivn], tcc = tfs[tid * 256 + ivn + 1];
          float dt2 = (tcc - tpp) * 0.5f;
          float ce = (gn & 3) == 0 ? 0.f : ((gn & 3) == 3 ? 1.f : 0.5f);
          float t = tpp + (float)(gn >> 2) * dt2 + ce * dt2;
          f16 th = (f16)t;
          xin[tid * XIN_S + 100] = th;
          xin[tid * XIN_S + 101] = (f16)(t - (float)th);
        }
      }
      if (dec && tid >= 504 && tid < 506) decL3(iv);
      __syncthreads();
    }
  }
  // ---- final decode: tf = 255 ----
  if (is3) decL1();
  __syncthreads();
  if (is1) decL2();
  __syncthreads();
  if (tid >= 504 && tid < 506) decL3(255);
}

extern "C" void kernel_launch(void* const* d_in, const int* in_sizes, int n_in,
                              void* d_out, int out_size, void* d_ws, size_t ws_size,
                              hipStream_t stream) {
  (void)in_sizes; (void)n_in; (void)out_size; (void)ws_size;
  const float* past     = (const float*)d_in[0];
  const float* h0       = (const float*)d_in[1];
  const float* t_future = (const float*)d_in[2];
  const float* eps      = (const float*)d_in[3];
  const float* fW1 = (const float*)d_in[4];  const float* fb1 = (const float*)d_in[5];
  const float* fW2 = (const float*)d_in[6];  const float* fb2 = (const float*)d_in[7];
  const float* fW3 = (const float*)d_in[8];  const float* fb3 = (const float*)d_in[9];
  const float* Wih = (const float*)d_in[10]; const float* Whh = (const float*)d_in[11];
  const float* bih = (const float*)d_in[12]; const float* bhh = (const float*)d_in[13];
  const float* gW1 = (const float*)d_in[14]; const float* gb1 = (const float*)d_in[15];
  const float* gW2 = (const float*)d_in[16]; const float* gb2 = (const float*)d_in[17];
  const float* gW3 = (const float*)d_in[18]; const float* gb3 = (const float*)d_in[19];
  const float* oW1 = (const float*)d_in[20]; const float* ob1 = (const float*)d_in[21];
  const float* oW2 = (const float*)d_in[22]; const float* ob2 = (const float*)d_in[23];
  const float* oW3 = (const float*)d_in[24]; const float* ob3 = (const float*)d_in[25];
  float* gxws = (float*)d_ws;
  float* out = (float*)d_out;

  hipLaunchKernelGGL(k_encode, dim3(128), dim3(512), 0, stream,
      past, h0, fW1, fb1, fW2, fb2, fW3, fb3,
      Wih, Whh, bih, bhh, gW1, gb1, gW2, gb2, gW3, gb3, gxws);
  hipLaunchKernelGGL(k_forecast, dim3(128), dim3(512), 0, stream,
      t_future, eps, fW1, fb1, fW2, fb2, fW3, fb3,
      oW1, ob1, oW2, ob2, oW3, ob3, gxws, out);
}

// Round 9
// 6260.759 us; speedup vs baseline: 1.6983x; 1.0640x over previous
//
#include <hip/hip_runtime.h>
#include <hip/hip_fp16.h>

typedef _Float16 f16;
typedef _Float16 f16x2 __attribute__((ext_vector_type(2)));
typedef _Float16 f16x4 __attribute__((ext_vector_type(4)));
typedef _Float16 f16x8 __attribute__((ext_vector_type(8)));
typedef float    f32x4 __attribute__((ext_vector_type(4)));

#define DEVI __device__ __forceinline__

DEVI float fdot2v(f16x2 a, f16x2 b, float c){
#if __has_builtin(__builtin_amdgcn_fdot2)
  return __builtin_amdgcn_fdot2(a, b, c, false);
#else
  return c + (float)a.x * (float)b.x + (float)a.y * (float)b.y;
#endif
}
DEVI f32x4 MM(f16x8 a, f16x8 b, f32x4 c){
  return __builtin_amdgcn_mfma_f32_16x16x32_f16(a, b, c, 0, 0, 0);
}
DEVI float tanh_f(float x){ return 1.f - 2.f / (__expf(2.f * x) + 1.f); }
DEVI float sigm_f(float x){ return 1.f / (1.f + __expf(-x)); }
DEVI float leaky_f(float x){ return x >= 0.f ? x : x * (1.0f / 5.5f); }

DEVI f16x8 ld8(const f16* p){ return *(const f16x8*)p; }

DEVI float dot8(f16x8 a, f16x8 b, float acc){
  union { f16x8 v; f16x2 h[4]; } ua, ub; ua.v = a; ub.v = b;
  acc = fdot2v(ua.h[0], ub.h[0], acc);
  acc = fdot2v(ua.h[1], ub.h[1], acc);
  acc = fdot2v(ua.h[2], ub.h[2], acc);
  acc = fdot2v(ua.h[3], ub.h[3], acc);
  return acc;
}

// A-fragment loader for mfma_f32_16x16x32_f16 (layout verified R6-R8).
// lane holds A[m = MT + (lane&15)][k = ks*32 + (lane>>4)*8 + j], j=0..7.
// col map: c<Kreal -> W[m*stride + c + coff]; c==tc0||tc1 -> W[m*stride];
// c==bc -> bias[m]; else 0. m >= rows -> 0.
DEVI f16x8 afrag(const float* W, const float* bias, int rows, int stride,
                 int Kreal, int coff, int tc0, int tc1, int bc,
                 int MT, int ks, int lane){
  int m  = MT + (lane & 15);
  int k0 = ks * 32 + ((lane >> 4) << 3);
  f16x8 v;
#pragma unroll
  for (int j = 0; j < 8; j++){
    int c = k0 + j; float x = 0.f;
    if (m < rows){
      if (c < Kreal)                 x = W[m * stride + c + coff];
      else if (c == tc0 || c == tc1) x = W[m * stride];
      else if (c == bc)              x = bias[m];
    }
    v[j] = (f16)x;
  }
  return v;
}

#define XIN_S 160   // f16: 0..99=y, 100=t_hi, 101=t_lo, 102=1.0, pad 0
#define X12_S 288   // f16: 0..274=act, 275=1.0(bias), pad 0
#define R1_S  304   // f32 raw stage1/2 pre-activations
#define R3_S  112   // f32 raw stage3
#define O_S   80    // f16 decoder acts, pad 0
#define OW1_S 104   // f16 decoder W1 row, pad 0
#define OW2_S 80    // f16 decoder W2 row, pad 0

// ===================== Kernel 1: encoder + latent MLP =====================
// 256 blocks x 256 threads (4 waves, 1/SIMD), 1 batch row per block.
__global__ __launch_bounds__(256, 1) void k_encode(
    const float* __restrict__ past, const float* __restrict__ h0,
    const float* __restrict__ fW1, const float* __restrict__ fb1,
    const float* __restrict__ fW2, const float* __restrict__ fb2,
    const float* __restrict__ fW3, const float* __restrict__ fb3,
    const float* __restrict__ Wih, const float* __restrict__ Whh,
    const float* __restrict__ bih, const float* __restrict__ bhh,
    const float* __restrict__ gW1, const float* __restrict__ gb1,
    const float* __restrict__ gW2, const float* __restrict__ gb2,
    const float* __restrict__ gW3, const float* __restrict__ gb3,
    float* __restrict__ gxws)
{
  __shared__ alignas(16) f16   xin[XIN_S];
  __shared__ alignas(16) f16   x1s[X12_S];
  __shared__ alignas(16) f16   x2s[X12_S];
  __shared__ alignas(16) float r1 [R1_S];
  __shared__ alignas(16) float r3 [R3_S];
  __shared__ alignas(16) float yfs[112];
  __shared__ alignas(16) float kas[112];
  __shared__ alignas(16) f16   ghs[304];
  __shared__ alignas(16) float pas[64];
  __shared__ alignas(16) float wihL[300];
  __shared__ alignas(16) float bihL[300];

  const int tid = threadIdx.x, blk = blockIdx.x;
  const int lane = tid & 63, w = tid >> 6;
  const int q = lane >> 4, n16 = lane & 15;
  const int bq = q * 8;

  const bool v5  = (w < 2);   // 5th tile in S1/S2 (tiles 16,17)
  const bool v32 = (w < 3);   // 2nd tile in S3 (tiles 4,5,6)

  // each wave holds fragments for ALL stages (fits at 1 wave/SIMD, 512-reg budget)
  f16x8 wf1[5][4], wf2[5][9], wf3[2][9];
#pragma unroll
  for (int ks = 0; ks < 4; ks++){
#pragma unroll
    for (int i = 0; i < 4; i++)
      wf1[i][ks] = afrag(fW1, fb1, 275, 101, 100, 1, 100, 101, 102, (4*i + w)*16, ks, lane);
    wf1[4][ks] = v5 ? afrag(fW1, fb1, 275, 101, 100, 1, 100, 101, 102, (16+w)*16, ks, lane)
                    : (f16x8)(f16)0.f;
  }
#pragma unroll
  for (int ks = 0; ks < 9; ks++){
#pragma unroll
    for (int i = 0; i < 4; i++)
      wf2[i][ks] = afrag(fW2, fb2, 275, 275, 275, 0, -1, -1, 275, (4*i + w)*16, ks, lane);
    wf2[4][ks] = v5 ? afrag(fW2, fb2, 275, 275, 275, 0, -1, -1, 275, (16+w)*16, ks, lane)
                    : (f16x8)(f16)0.f;
    wf3[0][ks] = afrag(fW3, fb3, 100, 275, 275, 0, -1, -1, 275, w*16, ks, lane);
    wf3[1][ks] = v32 ? afrag(fW3, fb3, 100, 275, 275, 0, -1, -1, 275, (4+w)*16, ks, lane)
                     : (f16x8)(f16)0.f;
  }

  // init
  for (int i = tid; i < XIN_S; i += 256) xin[i] = (f16)0.f;
  for (int i = tid; i < X12_S; i += 256){ x1s[i] = (f16)0.f; x2s[i] = (f16)0.f; }
  for (int i = tid; i < 64; i += 256) pas[i] = past[blk * 64 + i];
  for (int i = tid; i < 300; i += 256){ wihL[i] = Wih[i]; bihL[i] = bih[i]; }
  __syncthreads();
  if (tid < 100){
    float v = h0[blk * 100 + tid];
    yfs[tid] = v; xin[tid] = (f16)v;
  }
  if (tid == 0){
    xin[102] = (f16)1.f; x1s[275] = (f16)1.f; x2s[275] = (f16)1.f;
    float t0 = pas[0] - 1.f;
    f16 th = (f16)t0;
    xin[100] = th; xin[101] = (f16)(t0 - (float)th);
  }
  __syncthreads();

#pragma unroll 1
  for (int st = 0; st < 32; st++){
#pragma unroll 1
    for (int g = 0; g < 8; g++){
      // ---- P1: stage 1 MFMA ----
      {
        f32x4 a0={0,0,0,0}, a1=a0, a2=a0, a3=a0, a4=a0;
#pragma unroll
        for (int ks = 0; ks < 4; ks++){
          f16x8 b = ld8(xin + ks * 32 + bq);
          a0 = MM(wf1[0][ks], b, a0); a1 = MM(wf1[1][ks], b, a1);
          a2 = MM(wf1[2][ks], b, a2); a3 = MM(wf1[3][ks], b, a3);
          if (v5) a4 = MM(wf1[4][ks], b, a4);
        }
        if (n16 == 0){
          *(f32x4*)(r1 + (w     )*16 + q*4) = a0;
          *(f32x4*)(r1 + (4 + w )*16 + q*4) = a1;
          *(f32x4*)(r1 + (8 + w )*16 + q*4) = a2;
          *(f32x4*)(r1 + (12 + w)*16 + q*4) = a3;
          if (v5) *(f32x4*)(r1 + (16 + w)*16 + q*4) = a4;
        }
      }
      __syncthreads();
      // ---- P1b: tanh -> x1s ----
      x1s[tid] = (f16)tanh_f(r1[tid]);
      if (tid < 19) x1s[256 + tid] = (f16)tanh_f(r1[256 + tid]);
      __syncthreads();
      // ---- P2: stage 2 MFMA ----
      {
        f32x4 a0={0,0,0,0}, a1=a0, a2=a0, a3=a0, a4=a0;
#pragma unroll
        for (int ks = 0; ks < 9; ks++){
          f16x8 b = ld8(x1s + ks * 32 + bq);
          a0 = MM(wf2[0][ks], b, a0); a1 = MM(wf2[1][ks], b, a1);
          a2 = MM(wf2[2][ks], b, a2); a3 = MM(wf2[3][ks], b, a3);
          if (v5) a4 = MM(wf2[4][ks], b, a4);
        }
        if (n16 == 0){
          *(f32x4*)(r1 + (w     )*16 + q*4) = a0;
          *(f32x4*)(r1 + (4 + w )*16 + q*4) = a1;
          *(f32x4*)(r1 + (8 + w )*16 + q*4) = a2;
          *(f32x4*)(r1 + (12 + w)*16 + q*4) = a3;
          if (v5) *(f32x4*)(r1 + (16 + w)*16 + q*4) = a4;
        }
      }
      __syncthreads();
      // ---- P2b: tanh -> x2s ----
      x2s[tid] = (f16)tanh_f(r1[tid]);
      if (tid < 19) x2s[256 + tid] = (f16)tanh_f(r1[256 + tid]);
      __syncthreads();
      // ---- P3: stage 3 MFMA ----
      {
        f32x4 d0={0,0,0,0}, d1=d0;
#pragma unroll
        for (int ks = 0; ks < 9; ks++){
          f16x8 b = ld8(x2s + ks * 32 + bq);
          d0 = MM(wf3[0][ks], b, d0);
          if (v32) d1 = MM(wf3[1][ks], b, d1);
        }
        if (n16 == 0){
          *(f32x4*)(r3 + w*16 + q*4) = d0;
          if (v32) *(f32x4*)(r3 + (4 + w)*16 + q*4) = d1;
        }
      }
      __syncthreads();
      // ---- P3b: RK glue + t-update ----
      if (tid < 100){
        float tc = pas[2 * st];
        float tp = (st == 0) ? tc - 1.f : pas[2 * st - 2];
        float dt = (tc - tp) * 0.5f;
        float kv = tanh_f(r3[tid]);
        float y  = yfs[tid], ka = kas[tid], yst;
        int e = g & 3;
        if (e == 0){ kas[tid] = kv;            yst = y + 0.5f * dt * kv; }
        else if (e == 1){ kas[tid] = ka + 2.f * kv; yst = y + 0.5f * dt * kv; }
        else if (e == 2){ kas[tid] = ka + 2.f * kv; yst = y + dt * kv; }
        else { float yn = y + dt * (ka + kv) * (1.f / 6.f); yfs[tid] = yn; yst = yn; }
        xin[tid] = (f16)yst;
      }
      if (tid == 0 && g < 7){
        int gn = g + 1;
        float tc = pas[2 * st];
        float tp = (st == 0) ? tc - 1.f : pas[2 * st - 2];
        float dt2 = (tc - tp) * 0.5f;
        float ce = (gn & 3) == 0 ? 0.f : ((gn & 3) == 3 ? 1.f : 0.5f);
        float t = tp + (float)(gn >> 2) * dt2 + ce * dt2;
        f16 th = (f16)t;
        xin[100] = th; xin[101] = (f16)(t - (float)th);
      }
      __syncthreads();
    }
    // ---- P4: gh = Whh @ h + bhh (on-the-fly frags, 19 tiles) ----
    {
      f16x8 b0 = ld8(xin + 0  + bq), b1 = ld8(xin + 32 + bq),
            b2 = ld8(xin + 64 + bq), b3 = ld8(xin + 96 + bq);
#pragma unroll
      for (int i = 0; i < 5; i++){
        if (i == 4 && w >= 3) break;
        int MT = ((i < 4) ? (4*i + w) : (16 + w)) * 16;
        f32x4 d = {0.f,0.f,0.f,0.f};
        d = MM(afrag(Whh, bhh, 300, 100, 100, 0, -1, -1, 102, MT, 0, lane), b0, d);
        d = MM(afrag(Whh, bhh, 300, 100, 100, 0, -1, -1, 102, MT, 1, lane), b1, d);
        d = MM(afrag(Whh, bhh, 300, 100, 100, 0, -1, -1, 102, MT, 2, lane), b2, d);
        d = MM(afrag(Whh, bhh, 300, 100, 100, 0, -1, -1, 102, MT, 3, lane), b3, d);
        if (n16 == 0){
          f16x4 s; s[0]=(f16)d[0]; s[1]=(f16)d[1]; s[2]=(f16)d[2]; s[3]=(f16)d[3];
          *(f16x4*)(ghs + MT + q * 4) = s;
        }
      }
    }
    __syncthreads();
    // ---- P5: GRU gates ----
    if (tid < 100){
      float x = pas[2 * st + 1];
      float r  = sigm_f(x * wihL[tid]       + bihL[tid]       + (float)ghs[tid]);
      float z  = sigm_f(x * wihL[100 + tid] + bihL[100 + tid] + (float)ghs[100 + tid]);
      float nn = tanh_f(x * wihL[200 + tid] + bihL[200 + tid] + r * (float)ghs[200 + tid]);
      float h = yfs[tid];
      float hn = (1.f - z) * nn + z * h;
      yfs[tid] = hn; xin[tid] = (f16)hn;
    }
    if (tid == 0 && st < 31){
      float t = pas[2 * st];   // next interval starts at times[st]
      f16 th = (f16)t;
      xin[100] = th; xin[101] = (f16)(t - (float)th);
    }
    __syncthreads();
  }

  // ---- latent MLP (f32, once) ----
  if (tid < 75){
    float a = gb1[tid];
    for (int k = 0; k < 100; k++) a += gW1[tid * 100 + k] * yfs[k];
    r1[tid] = leaky_f(a);
  }
  __syncthreads();
  if (tid < 75){
    float a = gb2[tid];
    for (int k = 0; k < 75; k++) a += gW2[tid * 75 + k] * r1[k];
    r3[tid] = leaky_f(a);
  }
  __syncthreads();
  if (tid < 2){
    float a = gb3[tid];
    for (int k = 0; k < 75; k++) a += gW3[tid * 75 + k] * r3[k];
    gxws[blk * 2 + tid] = a;
  }
}

// ===================== Kernel 2: z0 + forecast ODE + decoder =====================
__global__ __launch_bounds__(256, 1) void k_forecast(
    const float* __restrict__ t_future, const float* __restrict__ eps,
    const float* __restrict__ fW1, const float* __restrict__ fb1,
    const float* __restrict__ fW2, const float* __restrict__ fb2,
    const float* __restrict__ fW3, const float* __restrict__ fb3,
    const float* __restrict__ oW1, const float* __restrict__ ob1,
    const float* __restrict__ oW2, const float* __restrict__ ob2,
    const float* __restrict__ oW3, const float* __restrict__ ob3,
    const float* __restrict__ gxws, float* __restrict__ out)
{
  __shared__ alignas(16) f16   xin[XIN_S];
  __shared__ alignas(16) f16   x1s[X12_S];
  __shared__ alignas(16) f16   x2s[X12_S];
  __shared__ alignas(16) float r1 [R1_S];
  __shared__ alignas(16) float r3 [R3_S];
  __shared__ alignas(16) float yfs[112];
  __shared__ alignas(16) float kas[112];
  __shared__ alignas(16) float tfs[256];
  __shared__ alignas(16) f16   o1s[O_S];
  __shared__ alignas(16) f16   o2s[O_S];
  __shared__ alignas(16) f16   oW1L[75 * OW1_S];
  __shared__ alignas(16) f16   oW2L[75 * OW2_S];
  __shared__ alignas(16) f16   ow3L[80];
  __shared__ alignas(16) float ob1L[75];
  __shared__ alignas(16) float ob2L[75];

  const int tid = threadIdx.x, blk = blockIdx.x;
  const int lane = tid & 63, w = tid >> 6;
  const int q = lane >> 4, n16 = lane & 15;
  const int bq = q * 8;

  const bool v5  = (w < 2);
  const bool v32 = (w < 3);

  f16x8 wf1[5][4], wf2[5][9], wf3[2][9];
#pragma unroll
  for (int ks = 0; ks < 4; ks++){
#pragma unroll
    for (int i = 0; i < 4; i++)
      wf1[i][ks] = afrag(fW1, fb1, 275, 101, 100, 1, 100, 101, 102, (4*i + w)*16, ks, lane);
    wf1[4][ks] = v5 ? afrag(fW1, fb1, 275, 101, 100, 1, 100, 101, 102, (16+w)*16, ks, lane)
                    : (f16x8)(f16)0.f;
  }
#pragma unroll
  for (int ks = 0; ks < 9; ks++){
#pragma unroll
    for (int i = 0; i < 4; i++)
      wf2[i][ks] = afrag(fW2, fb2, 275, 275, 275, 0, -1, -1, 275, (4*i + w)*16, ks, lane);
    wf2[4][ks] = v5 ? afrag(fW2, fb2, 275, 275, 275, 0, -1, -1, 275, (16+w)*16, ks, lane)
                    : (f16x8)(f16)0.f;
    wf3[0][ks] = afrag(fW3, fb3, 100, 275, 275, 0, -1, -1, 275, w*16, ks, lane);
    wf3[1][ks] = v32 ? afrag(fW3, fb3, 100, 275, 275, 0, -1, -1, 275, (4+w)*16, ks, lane)
                     : (f16x8)(f16)0.f;
  }
  const float ob3v = ob3[0];

  // init + decoder weight staging (f16 LDS, padded cols zero)
  for (int i = tid; i < XIN_S; i += 256) xin[i] = (f16)0.f;
  for (int i = tid; i < X12_S; i += 256){ x1s[i] = (f16)0.f; x2s[i] = (f16)0.f; }
  for (int i = tid; i < O_S; i += 256){ o1s[i] = (f16)0.f; o2s[i] = (f16)0.f; }
  for (int i = tid; i < 256; i += 256) tfs[i] = t_future[blk * 256 + i];
  for (int i = tid; i < 75 * OW1_S; i += 256){
    int r = i / OW1_S, c = i - r * OW1_S;
    oW1L[i] = (c < 100) ? (f16)oW1[r * 100 + c] : (f16)0.f;
  }
  for (int i = tid; i < 75 * OW2_S; i += 256){
    int r = i / OW2_S, c = i - r * OW2_S;
    oW2L[i] = (c < 75) ? (f16)oW2[r * 75 + c] : (f16)0.f;
  }
  if (tid < 80) ow3L[tid] = (tid < 75) ? (f16)oW3[tid] : (f16)0.f;
  if (tid < 75){ ob1L[tid] = ob1[tid]; ob2L[tid] = ob2[tid]; }
  __syncthreads();
  if (tid < 100){
    int r = blk;
    float loc, scl;
    if (r < 128){ loc = gxws[4 * r];              scl = gxws[4 * r + 2]; }
    else        { loc = fabsf(gxws[4 * r - 511]); scl = fabsf(gxws[4 * r - 509]); }
    float v = loc + scl * eps[tid * 256 + r];
    yfs[tid] = v; xin[tid] = (f16)v;
  }
  if (tid == 0){
    xin[102] = (f16)1.f; x1s[275] = (f16)1.f; x2s[275] = (f16)1.f;
    float t0 = tfs[0];
    f16 th = (f16)t0;
    xin[100] = th; xin[101] = (f16)(t0 - (float)th);
  }
  __syncthreads();

  auto decL1 = [&](){   // 75 outputs, K=104 (13 dot8), 2-way split over 150 thr
    if (tid < 150){
      int j = tid >> 1, s = tid & 1;
      float a = 0.f;
      const f16x8* wr = (const f16x8*)(oW1L + j * OW1_S);
      const f16x8* xr = (const f16x8*)xin;
#pragma unroll
      for (int c = 0; c < 7; c++){
        int cc = 7 * s + c;
        if (cc < 13) a = dot8(wr[cc], xr[cc], a);
      }
      a += __shfl_xor(a, 1);
      if (s == 0) o1s[j] = (f16)leaky_f(a + ob1L[j]);
    }
  };
  auto decL2 = [&](){   // 75 outputs, K=80 (10 dot8), 2-way split
    if (tid < 150){
      int j = tid >> 1, s = tid & 1;
      float a = 0.f;
      const f16x8* wr = (const f16x8*)(oW2L + j * OW2_S);
      const f16x8* xr = (const f16x8*)o1s;
#pragma unroll
      for (int c = 0; c < 5; c++){
        int cc = 5 * s + c;
        a = dot8(wr[cc], xr[cc], a);
      }
      a += __shfl_xor(a, 1);
      if (s == 0) o2s[j] = (f16)leaky_f(a + ob2L[j]);
    }
  };
  auto decL3 = [&](int tf){   // 1 output, 4-way split on tids 100-103 (lanes 36-39)
    if (tid >= 100 && tid < 104){
      int p = tid - 100;
      float a = 0.f;
      const f16x2* wv = (const f16x2*)ow3L;
      const f16x2* xv = (const f16x2*)o2s;
#pragma unroll
      for (int jj = 0; jj < 10; jj++) a = fdot2v(wv[10*p + jj], xv[10*p + jj], a);
      a += __shfl_xor(a, 1); a += __shfl_xor(a, 2);
      if (p == 0) out[blk * 256 + tf] = a + ob3v;
    }
  };

#pragma unroll 1
  for (int iv = 0; iv < 255; iv++){
#pragma unroll 1
    for (int g = 0; g < 8; g++){
      const bool dec = (g == 0);
      // ---- P1: stage 1 MFMA ----
      {
        f32x4 a0={0,0,0,0}, a1=a0, a2=a0, a3=a0, a4=a0;
#pragma unroll
        for (int ks = 0; ks < 4; ks++){
          f16x8 b = ld8(xin + ks * 32 + bq);
          a0 = MM(wf1[0][ks], b, a0); a1 = MM(wf1[1][ks], b, a1);
          a2 = MM(wf1[2][ks], b, a2); a3 = MM(wf1[3][ks], b, a3);
          if (v5) a4 = MM(wf1[4][ks], b, a4);
        }
        if (n16 == 0){
          *(f32x4*)(r1 + (w     )*16 + q*4) = a0;
          *(f32x4*)(r1 + (4 + w )*16 + q*4) = a1;
          *(f32x4*)(r1 + (8 + w )*16 + q*4) = a2;
          *(f32x4*)(r1 + (12 + w)*16 + q*4) = a3;
          if (v5) *(f32x4*)(r1 + (16 + w)*16 + q*4) = a4;
        }
      }
      __syncthreads();
      // ---- P1b: tanh -> x1s ; decoder L1 on start-of-interval state ----
      x1s[tid] = (f16)tanh_f(r1[tid]);
      if (tid < 19) x1s[256 + tid] = (f16)tanh_f(r1[256 + tid]);
      if (dec) decL1();
      __syncthreads();
      // ---- P2: stage 2 MFMA ----
      {
        f32x4 a0={0,0,0,0}, a1=a0, a2=a0, a3=a0, a4=a0;
#pragma unroll
        for (int ks = 0; ks < 9; ks++){
          f16x8 b = ld8(x1s + ks * 32 + bq);
          a0 = MM(wf2[0][ks], b, a0); a1 = MM(wf2[1][ks], b, a1);
          a2 = MM(wf2[2][ks], b, a2); a3 = MM(wf2[3][ks], b, a3);
          if (v5) a4 = MM(wf2[4][ks], b, a4);
        }
        if (n16 == 0){
          *(f32x4*)(r1 + (w     )*16 + q*4) = a0;
          *(f32x4*)(r1 + (4 + w )*16 + q*4) = a1;
          *(f32x4*)(r1 + (8 + w )*16 + q*4) = a2;
          *(f32x4*)(r1 + (12 + w)*16 + q*4) = a3;
          if (v5) *(f32x4*)(r1 + (16 + w)*16 + q*4) = a4;
        }
      }
      __syncthreads();
      // ---- P2b: tanh -> x2s ; decoder L2 ----
      x2s[tid] = (f16)tanh_f(r1[tid]);
      if (tid < 19) x2s[256 + tid] = (f16)tanh_f(r1[256 + tid]);
      if (dec) decL2();
      __syncthreads();
      // ---- P3: stage 3 MFMA ----
      {
        f32x4 d0={0,0,0,0}, d1=d0;
#pragma unroll
        for (int ks = 0; ks < 9; ks++){
          f16x8 b = ld8(x2s + ks * 32 + bq);
          d0 = MM(wf3[0][ks], b, d0);
          if (v32) d1 = MM(wf3[1][ks], b, d1);
        }
        if (n16 == 0){
          *(f32x4*)(r3 + w*16 + q*4) = d0;
          if (v32) *(f32x4*)(r3 + (4 + w)*16 + q*4) = d1;
        }
      }
      __syncthreads();
      // ---- P3b: RK glue + t-update ; decoder L3 ----
      if (tid < 100){
        float tp = tfs[iv], tc = tfs[iv + 1];
        float dt = (tc - tp) * 0.5f;
        float kv = tanh_f(r3[tid]);
        float y  = yfs[tid], ka = kas[tid], yst;
        int e = g & 3;
        if (e == 0){ kas[tid] = kv;                 yst = y + 0.5f * dt * kv; }
        else if (e == 1){ kas[tid] = ka + 2.f * kv; yst = y + 0.5f * dt * kv; }
        else if (e == 2){ kas[tid] = ka + 2.f * kv; yst = y + dt * kv; }
        else { float yn = y + dt * (ka + kv) * (1.f / 6.f); yfs[tid] = yn; yst = yn; }
        xin[tid] = (f16)yst;
      }
      if (tid == 0){
        int gn = g + 1, ivn = iv;
        if (gn == 8){ gn = 0; ivn = iv + 1; }
        if (ivn < 255){
          float tp = tfs[ivn], tc = tfs[ivn + 1];
          float dt2 = (tc - tp) * 0.5f;
          float ce = (gn & 3) == 0 ? 0.f : ((gn & 3) == 3 ? 1.f : 0.5f);
          float t = tp + (float)(gn >> 2) * dt2 + ce * dt2;
          f16 th = (f16)t;
          xin[100] = th; xin[101] = (f16)(t - (float)th);
        }
      }
      if (dec) decL3(iv);
      __syncthreads();
    }
  }
  // ---- final decode: tf = 255 on post-loop state ----
  decL1();
  __syncthreads();
  decL2();
  __syncthreads();
  decL3(255);
}

extern "C" void kernel_launch(void* const* d_in, const int* in_sizes, int n_in,
                              void* d_out, int out_size, void* d_ws, size_t ws_size,
                              hipStream_t stream) {
  (void)in_sizes; (void)n_in; (void)out_size; (void)ws_size;
  const float* past     = (const float*)d_in[0];
  const float* h0       = (const float*)d_in[1];
  const float* t_future = (const float*)d_in[2];
  const float* eps      = (const float*)d_in[3];
  const float* fW1 = (const float*)d_in[4];  const float* fb1 = (const float*)d_in[5];
  const float* fW2 = (const float*)d_in[6];  const float* fb2 = (const float*)d_in[7];
  const float* fW3 = (const float*)d_in[8];  const float* fb3 = (const float*)d_in[9];
  const float* Wih = (const float*)d_in[10]; const float* Whh = (const float*)d_in[11];
  const float* bih = (const float*)d_in[12]; const float* bhh = (const float*)d_in[13];
  const float* gW1 = (const float*)d_in[14]; const float* gb1 = (const float*)d_in[15];
  const float* gW2 = (const float*)d_in[16]; const float* gb2 = (const float*)d_in[17];
  const float* gW3 = (const float*)d_in[18]; const float* gb3 = (const float*)d_in[19];
  const float* oW1 = (const float*)d_in[20]; const float* ob1 = (const float*)d_in[21];
  const float* oW2 = (const float*)d_in[22]; const float* ob2 = (const float*)d_in[23];
  const float* oW3 = (const float*)d_in[24]; const float* ob3 = (const float*)d_in[25];
  float* gxws = (float*)d_ws;
  float* out = (float*)d_out;

  hipLaunchKernelGGL(k_encode, dim3(256), dim3(256), 0, stream,
      past, h0, fW1, fb1, fW2, fb2, fW3, fb3,
      Wih, Whh, bih, bhh, gW1, gb1, gW2, gb2, gW3, gb3, gxws);
  hipLaunchKernelGGL(k_forecast, dim3(256), dim3(256), 0, stream,
      t_future, eps, fW1, fb1, fW2, fb2, fW3, fb3,
      oW1, ob1, oW2, ob2, oW3, ob3, gxws, out);
}